// Round 13
// baseline (115.310 us; speedup 1.0000x reference)
//
#include <hip/hip_runtime.h>
#include <hip/hip_bf16.h>
#include <math.h>

// Problem constants
#define SS    256      // seq len
#define BB    4        // batch
#define HH    160      // hidden
#define NH_   8        // heads
#define HD_   20       // head dim
#define TBL   1025     // 2*MAXLEN+1
#define MAXL  512
#define FF_   640
#define PROWS 512      // live P rows: diff+256 in [1,511]

// setup-kernel block ranges
#define PT_TILES 64                    // 512 rows / 8
#define PT_PER_TAB (PT_TILES * 3)      // 192
#define PT_END (4 * PT_PER_TAB)        // 768
#define QKV_END (PT_END + 512)         // + (1024/16) x 8
#define WRT_END (QKV_END + 100)        // + 25600/256

__device__ __forceinline__ float blo(unsigned x) {
  return __uint_as_float(x << 16);
}
__device__ __forceinline__ float bhi(unsigned x) {
  return __uint_as_float(x & 0xffff0000u);
}

// ---------------------------------------------------------------------------
// Mega setup kernel: [0,768) ptab-as-GEMM -> bf16 P (rows 256..767 compact);
// [768,1280) QKV; [1280,1380) WrT.
// ---------------------------------------------------------------------------
__global__ __launch_bounds__(256) void k_setup(
    const float* __restrict__ pe_ss, const float* __restrict__ pe_se,
    const float* __restrict__ pe_es, const float* __restrict__ pe_ee,
    const float* __restrict__ W_fus, const float* __restrict__ b_fus,
    const float* __restrict__ inp,
    const float* __restrict__ Wq, const float* __restrict__ bq,
    const float* __restrict__ Wk, const float* __restrict__ bk,
    const float* __restrict__ Wv, const float* __restrict__ bv,
    const float* __restrict__ Wr,
    __hip_bfloat16* __restrict__ Pbf, float* __restrict__ qb,
    float* __restrict__ kb, float* __restrict__ vb, float* __restrict__ WrT) {
  int bid = blockIdx.x;
  int t = threadIdx.x;
  __shared__ __align__(16) float As[16][HH];

  if (bid < PT_END) {
    int tab = bid / PT_PER_TAB;
    int rem = bid - tab * PT_PER_TAB;
    int tile = rem / 3, yc = rem - tile * 3;
    int row0 = 256 + tile * 8;          // original rows 256..767
    const float* pe = (tab == 0) ? pe_ss : (tab == 1) ? pe_se
                    : (tab == 2) ? pe_es : pe_ee;
    for (int idx = t; idx < 8 * 40; idx += 256) {
      int r = idx / 40, c4 = idx - r * 40;
      *(float4*)&As[r][c4 * 4] =
          *(const float4*)(pe + (size_t)(row0 + r) * HH + c4 * 4);
    }
    __syncthreads();
    int c = (t & 63) + yc * 64;
    int wv = t >> 6;
    if (c < HH) {
      float acc0, acc1;
      acc0 = acc1 = (tab == 0) ? b_fus[c] : 0.0f;
      const float* wp = W_fus + (size_t)tab * HH * HH + c;
      int r0 = wv * 2, r1 = wv * 2 + 1;
      #pragma unroll 2
      for (int k = 0; k < HH; k += 8) {
        float w[8];
        #pragma unroll
        for (int q = 0; q < 8; ++q) w[q] = wp[(size_t)(k + q) * HH];
        float4 a0 = *(const float4*)&As[r0][k];
        float4 a1 = *(const float4*)&As[r0][k + 4];
        float4 b0 = *(const float4*)&As[r1][k];
        float4 b1_ = *(const float4*)&As[r1][k + 4];
        acc0 = fmaf(a0.x, w[0], acc0); acc0 = fmaf(a0.y, w[1], acc0);
        acc0 = fmaf(a0.z, w[2], acc0); acc0 = fmaf(a0.w, w[3], acc0);
        acc0 = fmaf(a1.x, w[4], acc0); acc0 = fmaf(a1.y, w[5], acc0);
        acc0 = fmaf(a1.z, w[6], acc0); acc0 = fmaf(a1.w, w[7], acc0);
        acc1 = fmaf(b0.x, w[0], acc1); acc1 = fmaf(b0.y, w[1], acc1);
        acc1 = fmaf(b0.z, w[2], acc1); acc1 = fmaf(b0.w, w[3], acc1);
        acc1 = fmaf(b1_.x, w[4], acc1); acc1 = fmaf(b1_.y, w[5], acc1);
        acc1 = fmaf(b1_.z, w[6], acc1); acc1 = fmaf(b1_.w, w[7], acc1);
      }
      int rloc = tile * 8;
      Pbf[((size_t)tab * PROWS + rloc + r0) * HH + c] = __float2bfloat16(acc0);
      Pbf[((size_t)tab * PROWS + rloc + r1) * HH + c] = __float2bfloat16(acc1);
    }
  } else if (bid < QKV_END) {
    int qbid = bid - PT_END;
    int bx = qbid & 63, by = qbid >> 6;
    int tok0 = bx * 16;
    {
      const float4* src = (const float4*)(inp + (size_t)tok0 * HH);
      float4* dst = (float4*)As;
      for (int idx = t; idx < 16 * HH / 4; idx += 256) dst[idx] = src[idx];
    }
    __syncthreads();
    int col = (t & 63) + by * 64;
    int wv = t >> 6;
    if (col < 480) {
      int mat = col / 160;
      int c = col - mat * 160;
      const float* W   = (mat == 0) ? Wq : (mat == 1) ? Wk : Wv;
      const float* bia = (mat == 0) ? bq : (mat == 1) ? bk : bv;
      float* O         = (mat == 0) ? qb : (mat == 1) ? kb : vb;
      float acc[4];
      float bb = bia[c];
      #pragma unroll
      for (int i = 0; i < 4; ++i) acc[i] = bb;
      const float* wp = W + c;
      #pragma unroll 2
      for (int k = 0; k < HH; k += 8) {
        float w[8];
        #pragma unroll
        for (int q = 0; q < 8; ++q) w[q] = wp[(size_t)(k + q) * HH];
        #pragma unroll
        for (int i = 0; i < 4; ++i) {
          const float4 a0 = *(const float4*)&As[wv * 4 + i][k];
          const float4 a1 = *(const float4*)&As[wv * 4 + i][k + 4];
          acc[i] = fmaf(a0.x, w[0], acc[i]);
          acc[i] = fmaf(a0.y, w[1], acc[i]);
          acc[i] = fmaf(a0.z, w[2], acc[i]);
          acc[i] = fmaf(a0.w, w[3], acc[i]);
          acc[i] = fmaf(a1.x, w[4], acc[i]);
          acc[i] = fmaf(a1.y, w[5], acc[i]);
          acc[i] = fmaf(a1.z, w[6], acc[i]);
          acc[i] = fmaf(a1.w, w[7], acc[i]);
        }
      }
      #pragma unroll
      for (int i = 0; i < 4; ++i)
        O[(size_t)(tok0 + wv * 4 + i) * HH + c] = acc[i];
    }
  } else {
    int o = (bid - QKV_END) * 256 + t;
    int cp = o / HH, cc = o - cp * HH;
    WrT[o] = Wr[(size_t)cc * HH + cp];
  }
}

// ---------------------------------------------------------------------------
// g-matrix precompute: gmat_bf[tok][h*160+cc] = bf16( sum_d (q+v)[20h+d]
//   * WrT[(20h+d)*160+cc] ).  grid 256, 4 tokens/block.
// ---------------------------------------------------------------------------
__global__ __launch_bounds__(256) void k_gmat(
    const float* __restrict__ qb, const float* __restrict__ vtab,
    const float* __restrict__ WrT, __hip_bfloat16* __restrict__ gmat_bf) {
  const int T = 4;
  int tok0 = blockIdx.x * T;
  int t = threadIdx.x;
  __shared__ __align__(16) float qs[T][HH];
  if (t < T * HH / 4) {
    int tt = t / 40, c4 = t - tt * 40;
    float4 q4 = *(const float4*)(qb + (size_t)(tok0 + tt) * HH + c4 * 4);
    float4 v4 = *(const float4*)(vtab + c4 * 4);
    q4.x += v4.x; q4.y += v4.y; q4.z += v4.z; q4.w += v4.w;
    *(float4*)&qs[tt][c4 * 4] = q4;
  }
  __syncthreads();
  #pragma unroll
  for (int r = 0; r < 5; ++r) {
    int p = r * 256 + t;                 // 0..1279
    int h = p / HH, cc = p - h * HH;
    float acc0 = 0.f, acc1 = 0.f, acc2 = 0.f, acc3 = 0.f;
    const float* wp = WrT + (size_t)(h * HD_) * HH + cc;
    #pragma unroll 4
    for (int d = 0; d < HD_; ++d) {
      float w = wp[(size_t)d * HH];
      acc0 = fmaf(qs[0][h * HD_ + d], w, acc0);
      acc1 = fmaf(qs[1][h * HD_ + d], w, acc1);
      acc2 = fmaf(qs[2][h * HD_ + d], w, acc2);
      acc3 = fmaf(qs[3][h * HD_ + d], w, acc3);
    }
    gmat_bf[(size_t)(tok0 + 0) * (NH_ * HH) + p] = __float2bfloat16(acc0);
    gmat_bf[(size_t)(tok0 + 1) * (NH_ * HH) + p] = __float2bfloat16(acc1);
    gmat_bf[(size_t)(tok0 + 2) * (NH_ * HH) + p] = __float2bfloat16(acc2);
    gmat_bf[(size_t)(tok0 + 3) * (NH_ * HH) + p] = __float2bfloat16(acc3);
  }
}

// ---------------------------------------------------------------------------
// LN1 + W1 + relu fused.
// ---------------------------------------------------------------------------
__global__ __launch_bounds__(256) void k_ffn1(
    const float* __restrict__ Y, const float* __restrict__ g1,
    const float* __restrict__ b1ln, const float* __restrict__ W1,
    const float* __restrict__ b1, float* __restrict__ Hb) {
  const int TT = 16;
  int tok0 = blockIdx.x * TT;
  int t = threadIdx.x;
  __shared__ __align__(16) float As[TT][HH];
  {
    const float4* src = (const float4*)(Y + (size_t)tok0 * HH);
    float4* dst = (float4*)As;
    for (int idx = t; idx < TT * HH / 4; idx += 256) dst[idx] = src[idx];
  }
  __syncthreads();
  {
    int row = t >> 4, l = t & 15;
    float s = 0.0f;
    #pragma unroll
    for (int c = l; c < HH; c += 16) s += As[row][c];
    #pragma unroll
    for (int m = 1; m < 16; m <<= 1) s += __shfl_xor(s, m);
    float mu = s * (1.0f / HH);
    float s2 = 0.0f;
    #pragma unroll
    for (int c = l; c < HH; c += 16) { float d = As[row][c] - mu; s2 = fmaf(d, d, s2); }
    #pragma unroll
    for (int m = 1; m < 16; m <<= 1) s2 += __shfl_xor(s2, m);
    float rstd = rsqrtf(s2 * (1.0f / HH) + 2.5e-6f);  // eps 1e-5 / 4
    #pragma unroll
    for (int c = l; c < HH; c += 16)
      As[row][c] = (As[row][c] - mu) * rstd * g1[c] + b1ln[c];
  }
  __syncthreads();
  int c = (t & 63) + blockIdx.y * 64;
  int wv = t >> 6;
  float acc[4];
  float bb = b1[c];
  #pragma unroll
  for (int i = 0; i < 4; ++i) acc[i] = bb;
  const float* wp = W1 + c;
  #pragma unroll 2
  for (int k = 0; k < HH; k += 8) {
    float w[8];
    #pragma unroll
    for (int q = 0; q < 8; ++q) w[q] = wp[(size_t)(k + q) * FF_];
    #pragma unroll
    for (int i = 0; i < 4; ++i) {
      const float4 a0 = *(const float4*)&As[wv * 4 + i][k];
      const float4 a1 = *(const float4*)&As[wv * 4 + i][k + 4];
      acc[i] = fmaf(a0.x, w[0], acc[i]);
      acc[i] = fmaf(a0.y, w[1], acc[i]);
      acc[i] = fmaf(a0.z, w[2], acc[i]);
      acc[i] = fmaf(a0.w, w[3], acc[i]);
      acc[i] = fmaf(a1.x, w[4], acc[i]);
      acc[i] = fmaf(a1.y, w[5], acc[i]);
      acc[i] = fmaf(a1.z, w[6], acc[i]);
      acc[i] = fmaf(a1.w, w[7], acc[i]);
    }
  }
  #pragma unroll
  for (int i = 0; i < 4; ++i)
    Hb[(size_t)(tok0 + wv * 4 + i) * FF_ + c] = fmaxf(acc[i], 0.0f);
}

// ---------------------------------------------------------------------------
// W2 GEMM with split-K=2 (no atomics): grid (M/4, 3, 2).  kz half computes
// K in [kz*320, kz*320+320); partials to y2a (kz=0, +bias) / y2b (kz=1).
// k_ln2 sums them.  Halves the serial load-chain, doubles block count.
// ---------------------------------------------------------------------------
__global__ __launch_bounds__(256) void k_w2(
    const float* __restrict__ A, const float* __restrict__ W2,
    const float* __restrict__ b2, float* __restrict__ y2a,
    float* __restrict__ y2b) {
  const int TT = 4, KH = 320;
  int tok0 = blockIdx.x * TT;
  int kz = blockIdx.z;
  int t = threadIdx.x;
  __shared__ __align__(16) float As[TT][KH];
  {
    const float* src = A + (size_t)tok0 * FF_ + kz * KH;
    for (int idx = t; idx < TT * KH / 4; idx += 256) {
      int tt = idx / (KH / 4), c4 = idx - tt * (KH / 4);
      *(float4*)&As[tt][c4 * 4] = *(const float4*)(src + (size_t)tt * FF_ + c4 * 4);
    }
  }
  __syncthreads();
  int c = (t & 63) + blockIdx.y * 64;
  int wv = t >> 6;
  if (c < HH) {
    float acc = (kz == 0) ? b2[c] : 0.0f;
    const float* wp = W2 + (size_t)(kz * KH) * HH + c;
    #pragma unroll 2
    for (int k = 0; k < KH; k += 8) {
      float w[8];
      #pragma unroll
      for (int q = 0; q < 8; ++q) w[q] = wp[(size_t)(k + q) * HH];
      const float4 a0 = *(const float4*)&As[wv][k];
      const float4 a1 = *(const float4*)&As[wv][k + 4];
      acc = fmaf(a0.x, w[0], acc);
      acc = fmaf(a0.y, w[1], acc);
      acc = fmaf(a0.z, w[2], acc);
      acc = fmaf(a0.w, w[3], acc);
      acc = fmaf(a1.x, w[4], acc);
      acc = fmaf(a1.y, w[5], acc);
      acc = fmaf(a1.z, w[6], acc);
      acc = fmaf(a1.w, w[7], acc);
    }
    float* O = (kz == 0) ? y2a : y2b;
    O[(size_t)(tok0 + wv) * HH + c] = acc;
  }
}

// ---------------------------------------------------------------------------
// Score kernel: bf16 P gather + precomputed bf16 gmat.  grid 4096 =
// (b,i) x j-quarter (64 j); 256 threads; wave w owns tile w (16 j).
// ---------------------------------------------------------------------------
#define RSTR 164
#define SCP  68    // sc_s row stride (272B, 16B aligned)

__global__ __launch_bounds__(256, 4) void k_score(
    const float* __restrict__ qb, const float* __restrict__ kb,
    const __hip_bfloat16* __restrict__ gmat_bf,
    const __hip_bfloat16* __restrict__ Pbf,
    const int* __restrict__ pos_s, const int* __restrict__ pos_e,
    const int* __restrict__ seq_len, const int* __restrict__ lex_num,
    const float* __restrict__ utab, float* __restrict__ scores) {
  int bid = blockIdx.x;
  int blk = bid >> 2;          // b*S + i
  int qtr = bid & 3;
  int b = blk >> 8;
  int i = blk & 255;
  int t = threadIdx.x;
  int limit = seq_len[b] + lex_num[0];
  if (qtr * 64 >= limit) return;   // whole quarter masked (uniform)

  __shared__ __align__(16) float qu[HH];
  __shared__ __align__(16) float g_s[NH_][RSTR];
  __shared__ __align__(16) float sc_s[NH_][SCP];
  __shared__ int ps_s[SS], pe_s[SS];

  if (t < HH) qu[t] = qb[(size_t)blk * HH + t] + utab[t];
  ps_s[t] = pos_s[b * SS + t];
  pe_s[t] = pos_e[b * SS + t];
  // g load: 160 uint4 = 1280 bf16, coalesced; unpack to f32 LDS
  if (t < 160) {
    const uint4* gsrc = (const uint4*)(gmat_bf + (size_t)blk * (NH_ * HH));
    uint4 u = gsrc[t];
    int h = t / 20, c8 = (t - h * 20) * 8;
    g_s[h][c8 + 0] = blo(u.x); g_s[h][c8 + 1] = bhi(u.x);
    g_s[h][c8 + 2] = blo(u.y); g_s[h][c8 + 3] = bhi(u.y);
    g_s[h][c8 + 4] = blo(u.z); g_s[h][c8 + 5] = bhi(u.z);
    g_s[h][c8 + 6] = blo(u.w); g_s[h][c8 + 7] = bhi(u.w);
  }
  __syncthreads();

  int w = t >> 6, lane = t & 63;
  int jj = lane >> 2, cg = lane & 3;
  int psi = ps_s[i], pei = pe_s[i];
  const float scale = 0.22360679774997896f;  // 1/sqrt(20)

  // bf16 planes: row stride = 160*2B = 20 uint4; plane = 512 rows.
  const uint4* Pb0 = (const uint4*)Pbf;
  const uint4* Pb1 = Pb0 + (size_t)PROWS * 20;
  const uint4* Pb2 = Pb1 + (size_t)PROWS * 20;
  const uint4* Pb3 = Pb2 + (size_t)PROWS * 20;
  const float4* kb4 = (const float4*)(kb + (size_t)b * SS * HH);

  int jl = w * 16 + jj;            // 0..63 within quarter
  int j = qtr * 64 + jl;
  if (qtr * 64 + w * 16 < limit) {   // tile not fully masked (wave-uniform)
    int psj = ps_s[j], pej = pe_s[j];
    int r0b = (psi - psj + 256) * 20;
    int r1b = (psi - pej + 256) * 20;
    int r2b = (pei - psj + 256) * 20;
    int r3b = (pei - pej + 256) * 20;
    float bd[NH_];
    #pragma unroll
    for (int h = 0; h < NH_; ++h) bd[h] = 0.0f;
    // gather: 4 uint4 (32 bf16) -> unpack -> relu -> 64 FMAs, per q5
    #pragma unroll 2
    for (int q5 = 0; q5 < 5; ++q5) {
      int off = q5 * 4 + cg;
      uint4 u0 = Pb0[r0b + off];
      uint4 u1 = Pb1[r1b + off];
      uint4 u2 = Pb2[r2b + off];
      uint4 u3 = Pb3[r3b + off];
      float rl[8];
      rl[0] = fmaxf(blo(u0.x) + blo(u1.x) + blo(u2.x) + blo(u3.x), 0.0f);
      rl[1] = fmaxf(bhi(u0.x) + bhi(u1.x) + bhi(u2.x) + bhi(u3.x), 0.0f);
      rl[2] = fmaxf(blo(u0.y) + blo(u1.y) + blo(u2.y) + blo(u3.y), 0.0f);
      rl[3] = fmaxf(bhi(u0.y) + bhi(u1.y) + bhi(u2.y) + bhi(u3.y), 0.0f);
      rl[4] = fmaxf(blo(u0.z) + blo(u1.z) + blo(u2.z) + blo(u3.z), 0.0f);
      rl[5] = fmaxf(bhi(u0.z) + bhi(u1.z) + bhi(u2.z) + bhi(u3.z), 0.0f);
      rl[6] = fmaxf(blo(u0.w) + blo(u1.w) + blo(u2.w) + blo(u3.w), 0.0f);
      rl[7] = fmaxf(bhi(u0.w) + bhi(u1.w) + bhi(u2.w) + bhi(u3.w), 0.0f);
      int cb = off * 8;
      #pragma unroll
      for (int h = 0; h < NH_; ++h) {
        float4 ga = *(const float4*)&g_s[h][cb];
        float4 gb = *(const float4*)&g_s[h][cb + 4];
        bd[h] = fmaf(rl[0], ga.x, bd[h]);
        bd[h] = fmaf(rl[1], ga.y, bd[h]);
        bd[h] = fmaf(rl[2], ga.z, bd[h]);
        bd[h] = fmaf(rl[3], ga.w, bd[h]);
        bd[h] = fmaf(rl[4], gb.x, bd[h]);
        bd[h] = fmaf(rl[5], gb.y, bd[h]);
        bd[h] = fmaf(rl[6], gb.z, bd[h]);
        bd[h] = fmaf(rl[7], gb.w, bd[h]);
      }
    }
    // A_C for heads 2cg, 2cg+1 : c in [40cg, 40cg+40)
    float ac0 = 0.0f, ac1 = 0.0f;
    {
      int kbase = j * 40 + 10 * cg;
      #pragma unroll
      for (int m = 0; m < 10; ++m) {
        float4 kv = kb4[kbase + m];
        float4 q4 = *(const float4*)&qu[(10 * cg + m) * 4];
        if (m < 5) {
          ac0 = fmaf(q4.x, kv.x, ac0); ac0 = fmaf(q4.y, kv.y, ac0);
          ac0 = fmaf(q4.z, kv.z, ac0); ac0 = fmaf(q4.w, kv.w, ac0);
        } else {
          ac1 = fmaf(q4.x, kv.x, ac1); ac1 = fmaf(q4.y, kv.y, ac1);
          ac1 = fmaf(q4.z, kv.z, ac1); ac1 = fmaf(q4.w, kv.w, ac1);
        }
      }
    }
    // reduce bd over the 4 cg lanes
    #pragma unroll
    for (int h = 0; h < NH_; ++h) {
      bd[h] += __shfl_xor(bd[h], 1);
      bd[h] += __shfl_xor(bd[h], 2);
    }
    float s0, s1;
    if      (cg == 0) { s0 = bd[0]; s1 = bd[1]; }
    else if (cg == 1) { s0 = bd[2]; s1 = bd[3]; }
    else if (cg == 2) { s0 = bd[4]; s1 = bd[5]; }
    else              { s0 = bd[6]; s1 = bd[7]; }
    sc_s[2 * cg][jl]     = (s0 + ac0) * scale;
    sc_s[2 * cg + 1][jl] = (s1 + ac1) * scale;
  }
  __syncthreads();

  // coalesced writeout: 8 rows x 16 float4 (threads 0..127)
  if (t < 128) {
    int row = t >> 4, c4 = t & 15;
    float4 v = *(const float4*)&sc_s[row][c4 * 4];
    *(float4*)&scores[((size_t)blk * NH_ + row) * SS + qtr * 64 + c4 * 4] = v;
  }
}

// ---------------------------------------------------------------------------
// Softmax + PV + W_fin fused: grid 1024, 256 threads.
// ---------------------------------------------------------------------------
#define SCS 260

__global__ __launch_bounds__(256, 4) void k_smpv(
    const float* __restrict__ scores, const float* __restrict__ vb,
    const int* __restrict__ seq_len, const int* __restrict__ lex_num,
    const float* __restrict__ W_fin, const float* __restrict__ b_fin,
    float* __restrict__ ybuf) {
  int blk = blockIdx.x;
  int b = blk >> 8;
  int t = threadIdx.x;
  __shared__ __align__(16) float sc[NH_][SCS];
  __shared__ __align__(16) float outs[HH];
  int limit = seq_len[b] + lex_num[0];

  const float4* src = (const float4*)(scores + (size_t)blk * NH_ * SS);
  #pragma unroll
  for (int r = 0; r < 2; ++r) {
    int idx = r * 256 + t;
    int row = idx >> 6, c4 = idx & 63;
    float4 v = src[idx];
    int j0 = c4 * 4;
    v.x = (j0 + 0 < limit) ? v.x : -1.0e15f;
    v.y = (j0 + 1 < limit) ? v.y : -1.0e15f;
    v.z = (j0 + 2 < limit) ? v.z : -1.0e15f;
    v.w = (j0 + 3 < limit) ? v.w : -1.0e15f;
    *(float4*)&sc[row][j0] = v;
  }
  __syncthreads();

  {
    int h = t >> 5, l = t & 31;
    float m = -3.0e38f;
    float e[8];
    #pragma unroll
    for (int ii = 0; ii < 8; ++ii) m = fmaxf(m, sc[h][l + ii * 32]);
    #pragma unroll
    for (int msk = 16; msk; msk >>= 1) m = fmaxf(m, __shfl_xor(m, msk));
    float s = 0.0f;
    #pragma unroll
    for (int ii = 0; ii < 8; ++ii) { e[ii] = __expf(sc[h][l + ii * 32] - m); s += e[ii]; }
    #pragma unroll
    for (int msk = 16; msk; msk >>= 1) s += __shfl_xor(s, msk);
    float inv = 1.0f / s;
    #pragma unroll
    for (int ii = 0; ii < 8; ++ii) sc[h][l + ii * 32] = e[ii] * inv;
  }
  __syncthreads();

  if (t < HH) {
    int h = t / HD_;
    int lim4 = (limit + 3) & ~3;
    float acc0 = 0.f, acc1 = 0.f, acc2 = 0.f, acc3 = 0.f;
    const float* vcol = vb + (size_t)b * SS * HH + t;
    for (int j2 = 0; j2 < lim4; j2 += 4) {
      float4 p4 = *(const float4*)&sc[h][j2];
      acc0 = fmaf(p4.x, vcol[(size_t)(j2 + 0) * HH], acc0);
      acc1 = fmaf(p4.y, vcol[(size_t)(j2 + 1) * HH], acc1);
      acc2 = fmaf(p4.z, vcol[(size_t)(j2 + 2) * HH], acc2);
      acc3 = fmaf(p4.w, vcol[(size_t)(j2 + 3) * HH], acc3);
    }
    outs[t] = (acc0 + acc1) + (acc2 + acc3);
  }
  __syncthreads();

  // W_fin: y[t] = b_fin[t] + sum_c outs[c] * W_fin[c*160 + t]
  if (t < HH) {
    float acc = b_fin[t];
    const float* wp = W_fin + t;
    #pragma unroll 8
    for (int c = 0; c < HH; ++c)
      acc = fmaf(outs[c], wp[(size_t)c * HH], acc);
    ybuf[(size_t)blk * HH + t] = acc;
  }
}

// ---------------------------------------------------------------------------
// Final LayerNorm over sum of split-K partials.  LN(2(p1+p2)) == LN(p1+p2)
// with eps/4.
// ---------------------------------------------------------------------------
__global__ __launch_bounds__(256) void k_ln2(
    const float* __restrict__ Ya, const float* __restrict__ Yb,
    const float* __restrict__ g, const float* __restrict__ bln,
    float* __restrict__ O) {
  int tok = blockIdx.x * 4 + (threadIdx.x >> 6);
  int l = threadIdx.x & 63;
  const float* ya = Ya + (size_t)tok * HH;
  const float* yb = Yb + (size_t)tok * HH;
  float a = ya[l] + yb[l];
  float bv = ya[l + 64] + yb[l + 64];
  bool has3 = l < (HH - 128);
  float cv = has3 ? (ya[l + 128] + yb[l + 128]) : 0.0f;
  float s = a + bv + cv;
  #pragma unroll
  for (int m = 32; m; m >>= 1) s += __shfl_xor(s, m);
  float mu = s * (1.0f / HH);
  float da = a - mu, db = bv - mu, dc = has3 ? (cv - mu) : 0.0f;
  float s2 = da * da + db * db + dc * dc;
  #pragma unroll
  for (int m = 32; m; m >>= 1) s2 += __shfl_xor(s2, m);
  float rstd = rsqrtf(s2 * (1.0f / HH) + 2.5e-6f);  // eps 1e-5 / 4
  float* o = O + (size_t)tok * HH;
  o[l]      = da * rstd * g[l] + bln[l];
  o[l + 64] = db * rstd * g[l + 64] + bln[l + 64];
  if (has3) o[l + 128] = dc * rstd * g[l + 128] + bln[l + 128];
}

// ---------------------------------------------------------------------------
extern "C" void kernel_launch(void* const* d_in, const int* in_sizes, int n_in,
                              void* d_out, int out_size, void* d_ws, size_t ws_size,
                              hipStream_t stream) {
  const float* inp    = (const float*)d_in[0];
  const int*   pos_s  = (const int*)d_in[1];
  const int*   pos_e  = (const int*)d_in[2];
  const int*   seq_ln = (const int*)d_in[3];
  const int*   lex_nm = (const int*)d_in[4];
  const float* pe_ss  = (const float*)d_in[5];
  const float* pe_se  = (const float*)d_in[6];
  const float* pe_es  = (const float*)d_in[7];
  const float* pe_ee  = (const float*)d_in[8];
  const float* W_fus  = (const float*)d_in[9];
  const float* b_fus  = (const float*)d_in[10];
  const float* Wq     = (const float*)d_in[11];
  const float* bq     = (const float*)d_in[12];
  const float* Wk     = (const float*)d_in[13];
  const float* bk     = (const float*)d_in[14];
  const float* Wv     = (const float*)d_in[15];
  const float* bv     = (const float*)d_in[16];
  const float* Wr     = (const float*)d_in[17];
  // d_in[18] = br : constant-over-j term, cancels in softmax
  const float* utab   = (const float*)d_in[19];
  const float* vtab   = (const float*)d_in[20];
  const float* W_fin  = (const float*)d_in[21];
  const float* b_fin  = (const float*)d_in[22];
  const float* ln1_g  = (const float*)d_in[23];
  const float* ln1_b  = (const float*)d_in[24];
  const float* W1     = (const float*)d_in[25];
  const float* b1     = (const float*)d_in[26];
  const float* W2     = (const float*)d_in[27];
  const float* b2     = (const float*)d_in[28];
  const float* ln2_g  = (const float*)d_in[29];
  const float* ln2_b  = (const float*)d_in[30];

  float* ws = (float*)d_ws;
  __hip_bfloat16* Pbf = (__hip_bfloat16*)ws;          // 4*512*160 bf16 = 655360 B
  float* qb       = ws + 163840;
  float* kb       = qb + BB * SS * HH;
  float* vb       = kb + BB * SS * HH;
  float* WrT      = vb + BB * SS * HH;                // 25600
  float* gregion  = WrT + HH * HH;                    // 655360 float-slots
  __hip_bfloat16* gmat_bf = (__hip_bfloat16*)gregion; //   1024*1280 bf16
  float* ybuf     = gregion;                          //   aliases gmat (dead after k_score)
  float* scores   = gregion + 655360;                 // 2097152 (1024*8*256)
  // scores dead after k_smpv; alias FFN buffers over it:
  float* hbuf     = scores;                           // 655360
  float* y2a      = scores + 655360;                  // 163840
  float* y2b      = scores + 819200;                  // 163840

  (void)in_sizes; (void)n_in; (void)out_size; (void)ws_size;

  const int M = BB * SS;  // 1024

  k_setup<<<WRT_END, 256, 0, stream>>>(pe_ss, pe_se, pe_es, pe_ee, W_fus, b_fus,
                                       inp, Wq, bq, Wk, bk, Wv, bv, Wr,
                                       Pbf, qb, kb, vb, WrT);
  k_gmat<<<M / 4, 256, 0, stream>>>(qb, vtab, WrT, gmat_bf);
  k_score<<<4 * M, 256, 0, stream>>>(qb, kb, gmat_bf, Pbf, pos_s, pos_e,
                                     seq_ln, lex_nm, utab, scores);
  k_smpv<<<M, 256, 0, stream>>>(scores, vb, seq_ln, lex_nm, W_fin, b_fin, ybuf);
  k_ffn1<<<dim3(M / 16, 10), 256, 0, stream>>>(ybuf, ln1_g, ln1_b, W1, b1, hbuf);
  k_w2<<<dim3(M / 4, 3, 2), 256, 0, stream>>>(hbuf, W2, b2, y2a, y2b);
  k_ln2<<<M / 4, 256, 0, stream>>>(y2a, y2b, ln2_g, ln2_b, (float*)d_out);
}

// Round 15
// 112.141 us; speedup vs baseline: 1.0283x; 1.0283x over previous
//
#include <hip/hip_runtime.h>
#include <hip/hip_bf16.h>
#include <math.h>

// Problem constants
#define SS    256      // seq len
#define BB    4        // batch
#define HH    160      // hidden
#define NH_   8        // heads
#define HD_   20       // head dim
#define TBL   1025     // 2*MAXLEN+1
#define MAXL  512
#define FF_   640
#define PROWS 512      // live P rows: diff+256 in [1,511]

// setup-kernel block ranges
#define PT_TILES 64                    // 512 rows / 8
#define PT_PER_TAB (PT_TILES * 3)      // 192
#define PT_END (4 * PT_PER_TAB)        // 768
#define QKV_END (PT_END + 512)         // + (1024/16) x 8
#define WRT_END (QKV_END + 100)        // + 25600/256

__device__ __forceinline__ float blo(unsigned x) {
  return __uint_as_float(x << 16);
}
__device__ __forceinline__ float bhi(unsigned x) {
  return __uint_as_float(x & 0xffff0000u);
}

// ---------------------------------------------------------------------------
// Mega setup kernel: [0,768) ptab-as-GEMM -> bf16 P (rows 256..767 compact);
// [768,1280) QKV; [1280,1380) WrT.
// ---------------------------------------------------------------------------
__global__ __launch_bounds__(256) void k_setup(
    const float* __restrict__ pe_ss, const float* __restrict__ pe_se,
    const float* __restrict__ pe_es, const float* __restrict__ pe_ee,
    const float* __restrict__ W_fus, const float* __restrict__ b_fus,
    const float* __restrict__ inp,
    const float* __restrict__ Wq, const float* __restrict__ bq,
    const float* __restrict__ Wk, const float* __restrict__ bk,
    const float* __restrict__ Wv, const float* __restrict__ bv,
    const float* __restrict__ Wr,
    __hip_bfloat16* __restrict__ Pbf, float* __restrict__ qb,
    float* __restrict__ kb, float* __restrict__ vb, float* __restrict__ WrT) {
  int bid = blockIdx.x;
  int t = threadIdx.x;
  __shared__ __align__(16) float As[16][HH];

  if (bid < PT_END) {
    int tab = bid / PT_PER_TAB;
    int rem = bid - tab * PT_PER_TAB;
    int tile = rem / 3, yc = rem - tile * 3;
    int row0 = 256 + tile * 8;          // original rows 256..767
    const float* pe = (tab == 0) ? pe_ss : (tab == 1) ? pe_se
                    : (tab == 2) ? pe_es : pe_ee;
    for (int idx = t; idx < 8 * 40; idx += 256) {
      int r = idx / 40, c4 = idx - r * 40;
      *(float4*)&As[r][c4 * 4] =
          *(const float4*)(pe + (size_t)(row0 + r) * HH + c4 * 4);
    }
    __syncthreads();
    int c = (t & 63) + yc * 64;
    int wv = t >> 6;
    if (c < HH) {
      float acc0, acc1;
      acc0 = acc1 = (tab == 0) ? b_fus[c] : 0.0f;
      const float* wp = W_fus + (size_t)tab * HH * HH + c;
      int r0 = wv * 2, r1 = wv * 2 + 1;
      #pragma unroll 2
      for (int k = 0; k < HH; k += 8) {
        float w[8];
        #pragma unroll
        for (int q = 0; q < 8; ++q) w[q] = wp[(size_t)(k + q) * HH];
        float4 a0 = *(const float4*)&As[r0][k];
        float4 a1 = *(const float4*)&As[r0][k + 4];
        float4 b0 = *(const float4*)&As[r1][k];
        float4 b1_ = *(const float4*)&As[r1][k + 4];
        acc0 = fmaf(a0.x, w[0], acc0); acc0 = fmaf(a0.y, w[1], acc0);
        acc0 = fmaf(a0.z, w[2], acc0); acc0 = fmaf(a0.w, w[3], acc0);
        acc0 = fmaf(a1.x, w[4], acc0); acc0 = fmaf(a1.y, w[5], acc0);
        acc0 = fmaf(a1.z, w[6], acc0); acc0 = fmaf(a1.w, w[7], acc0);
        acc1 = fmaf(b0.x, w[0], acc1); acc1 = fmaf(b0.y, w[1], acc1);
        acc1 = fmaf(b0.z, w[2], acc1); acc1 = fmaf(b0.w, w[3], acc1);
        acc1 = fmaf(b1_.x, w[4], acc1); acc1 = fmaf(b1_.y, w[5], acc1);
        acc1 = fmaf(b1_.z, w[6], acc1); acc1 = fmaf(b1_.w, w[7], acc1);
      }
      int rloc = tile * 8;
      Pbf[((size_t)tab * PROWS + rloc + r0) * HH + c] = __float2bfloat16(acc0);
      Pbf[((size_t)tab * PROWS + rloc + r1) * HH + c] = __float2bfloat16(acc1);
    }
  } else if (bid < QKV_END) {
    int qbid = bid - PT_END;
    int bx = qbid & 63, by = qbid >> 6;
    int tok0 = bx * 16;
    {
      const float4* src = (const float4*)(inp + (size_t)tok0 * HH);
      float4* dst = (float4*)As;
      for (int idx = t; idx < 16 * HH / 4; idx += 256) dst[idx] = src[idx];
    }
    __syncthreads();
    int col = (t & 63) + by * 64;
    int wv = t >> 6;
    if (col < 480) {
      int mat = col / 160;
      int c = col - mat * 160;
      const float* W   = (mat == 0) ? Wq : (mat == 1) ? Wk : Wv;
      const float* bia = (mat == 0) ? bq : (mat == 1) ? bk : bv;
      float* O         = (mat == 0) ? qb : (mat == 1) ? kb : vb;
      float acc[4];
      float bb = bia[c];
      #pragma unroll
      for (int i = 0; i < 4; ++i) acc[i] = bb;
      const float* wp = W + c;
      #pragma unroll 2
      for (int k = 0; k < HH; k += 8) {
        float w[8];
        #pragma unroll
        for (int q = 0; q < 8; ++q) w[q] = wp[(size_t)(k + q) * HH];
        #pragma unroll
        for (int i = 0; i < 4; ++i) {
          const float4 a0 = *(const float4*)&As[wv * 4 + i][k];
          const float4 a1 = *(const float4*)&As[wv * 4 + i][k + 4];
          acc[i] = fmaf(a0.x, w[0], acc[i]);
          acc[i] = fmaf(a0.y, w[1], acc[i]);
          acc[i] = fmaf(a0.z, w[2], acc[i]);
          acc[i] = fmaf(a0.w, w[3], acc[i]);
          acc[i] = fmaf(a1.x, w[4], acc[i]);
          acc[i] = fmaf(a1.y, w[5], acc[i]);
          acc[i] = fmaf(a1.z, w[6], acc[i]);
          acc[i] = fmaf(a1.w, w[7], acc[i]);
        }
      }
      #pragma unroll
      for (int i = 0; i < 4; ++i)
        O[(size_t)(tok0 + wv * 4 + i) * HH + c] = acc[i];
    }
  } else {
    int o = (bid - QKV_END) * 256 + t;
    int cp = o / HH, cc = o - cp * HH;
    WrT[o] = Wr[(size_t)cc * HH + cp];
  }
}

// ---------------------------------------------------------------------------
// g-matrix precompute: gmat_bf[tok][h*160+cc] = bf16( sum_d (q+v)[20h+d]
//   * WrT[(20h+d)*160+cc] ).  grid 256, 4 tokens/block.
// ---------------------------------------------------------------------------
__global__ __launch_bounds__(256) void k_gmat(
    const float* __restrict__ qb, const float* __restrict__ vtab,
    const float* __restrict__ WrT, __hip_bfloat16* __restrict__ gmat_bf) {
  const int T = 4;
  int tok0 = blockIdx.x * T;
  int t = threadIdx.x;
  __shared__ __align__(16) float qs[T][HH];
  if (t < T * HH / 4) {
    int tt = t / 40, c4 = t - tt * 40;
    float4 q4 = *(const float4*)(qb + (size_t)(tok0 + tt) * HH + c4 * 4);
    float4 v4 = *(const float4*)(vtab + c4 * 4);
    q4.x += v4.x; q4.y += v4.y; q4.z += v4.z; q4.w += v4.w;
    *(float4*)&qs[tt][c4 * 4] = q4;
  }
  __syncthreads();
  #pragma unroll
  for (int r = 0; r < 5; ++r) {
    int p = r * 256 + t;                 // 0..1279
    int h = p / HH, cc = p - h * HH;
    float acc0 = 0.f, acc1 = 0.f, acc2 = 0.f, acc3 = 0.f;
    const float* wp = WrT + (size_t)(h * HD_) * HH + cc;
    #pragma unroll 4
    for (int d = 0; d < HD_; ++d) {
      float w = wp[(size_t)d * HH];
      acc0 = fmaf(qs[0][h * HD_ + d], w, acc0);
      acc1 = fmaf(qs[1][h * HD_ + d], w, acc1);
      acc2 = fmaf(qs[2][h * HD_ + d], w, acc2);
      acc3 = fmaf(qs[3][h * HD_ + d], w, acc3);
    }
    gmat_bf[(size_t)(tok0 + 0) * (NH_ * HH) + p] = __float2bfloat16(acc0);
    gmat_bf[(size_t)(tok0 + 1) * (NH_ * HH) + p] = __float2bfloat16(acc1);
    gmat_bf[(size_t)(tok0 + 2) * (NH_ * HH) + p] = __float2bfloat16(acc2);
    gmat_bf[(size_t)(tok0 + 3) * (NH_ * HH) + p] = __float2bfloat16(acc3);
  }
}

// ---------------------------------------------------------------------------
// LN1 + W1 + relu fused.  TT=8 (grid 128x10 = 1280 blocks, 5/CU).
// LN: 32 lanes per row.  GEMM: 4 waves x 2 tokens each.
// ---------------------------------------------------------------------------
__global__ __launch_bounds__(256) void k_ffn1(
    const float* __restrict__ Y, const float* __restrict__ g1,
    const float* __restrict__ b1ln, const float* __restrict__ W1,
    const float* __restrict__ b1, float* __restrict__ Hb) {
  const int TT = 8;
  int tok0 = blockIdx.x * TT;
  int t = threadIdx.x;
  __shared__ __align__(16) float As[TT][HH];
  {
    const float4* src = (const float4*)(Y + (size_t)tok0 * HH);
    float4* dst = (float4*)As;
    for (int idx = t; idx < TT * HH / 4; idx += 256) dst[idx] = src[idx];  // 320 float4s, 2 iters
  }
  __syncthreads();
  {
    int row = t >> 5, l = t & 31;    // 8 rows x 32 lanes
    float s = 0.0f;
    #pragma unroll
    for (int c = l; c < HH; c += 32) s += As[row][c];
    #pragma unroll
    for (int m = 1; m < 32; m <<= 1) s += __shfl_xor(s, m);
    float mu = s * (1.0f / HH);
    float s2 = 0.0f;
    #pragma unroll
    for (int c = l; c < HH; c += 32) { float d = As[row][c] - mu; s2 = fmaf(d, d, s2); }
    #pragma unroll
    for (int m = 1; m < 32; m <<= 1) s2 += __shfl_xor(s2, m);
    float rstd = rsqrtf(s2 * (1.0f / HH) + 2.5e-6f);  // eps 1e-5 / 4
    #pragma unroll
    for (int c = l; c < HH; c += 32)
      As[row][c] = (As[row][c] - mu) * rstd * g1[c] + b1ln[c];
  }
  __syncthreads();
  int c = (t & 63) + blockIdx.y * 64;   // < 640 always
  int wv = t >> 6;
  float acc[2];
  float bb = b1[c];
  acc[0] = bb; acc[1] = bb;
  const float* wp = W1 + c;
  #pragma unroll 2
  for (int k = 0; k < HH; k += 8) {
    float w[8];
    #pragma unroll
    for (int q = 0; q < 8; ++q) w[q] = wp[(size_t)(k + q) * FF_];
    #pragma unroll
    for (int i = 0; i < 2; ++i) {
      const float4 a0 = *(const float4*)&As[wv * 2 + i][k];
      const float4 a1 = *(const float4*)&As[wv * 2 + i][k + 4];
      acc[i] = fmaf(a0.x, w[0], acc[i]);
      acc[i] = fmaf(a0.y, w[1], acc[i]);
      acc[i] = fmaf(a0.z, w[2], acc[i]);
      acc[i] = fmaf(a0.w, w[3], acc[i]);
      acc[i] = fmaf(a1.x, w[4], acc[i]);
      acc[i] = fmaf(a1.y, w[5], acc[i]);
      acc[i] = fmaf(a1.z, w[6], acc[i]);
      acc[i] = fmaf(a1.w, w[7], acc[i]);
    }
  }
  #pragma unroll
  for (int i = 0; i < 2; ++i)
    Hb[(size_t)(tok0 + wv * 2 + i) * FF_ + c] = fmaxf(acc[i], 0.0f);
}

// ---------------------------------------------------------------------------
// W2 GEMM with split-K=2 (no atomics): grid (M/4, 3, 2).
// ---------------------------------------------------------------------------
__global__ __launch_bounds__(256) void k_w2(
    const float* __restrict__ A, const float* __restrict__ W2,
    const float* __restrict__ b2, float* __restrict__ y2a,
    float* __restrict__ y2b) {
  const int TT = 4, KH = 320;
  int tok0 = blockIdx.x * TT;
  int kz = blockIdx.z;
  int t = threadIdx.x;
  __shared__ __align__(16) float As[TT][KH];
  {
    const float* src = A + (size_t)tok0 * FF_ + kz * KH;
    for (int idx = t; idx < TT * KH / 4; idx += 256) {
      int tt = idx / (KH / 4), c4 = idx - tt * (KH / 4);
      *(float4*)&As[tt][c4 * 4] = *(const float4*)(src + (size_t)tt * FF_ + c4 * 4);
    }
  }
  __syncthreads();
  int c = (t & 63) + blockIdx.y * 64;
  int wv = t >> 6;
  if (c < HH) {
    float acc = (kz == 0) ? b2[c] : 0.0f;
    const float* wp = W2 + (size_t)(kz * KH) * HH + c;
    #pragma unroll 2
    for (int k = 0; k < KH; k += 8) {
      float w[8];
      #pragma unroll
      for (int q = 0; q < 8; ++q) w[q] = wp[(size_t)(k + q) * HH];
      const float4 a0 = *(const float4*)&As[wv][k];
      const float4 a1 = *(const float4*)&As[wv][k + 4];
      acc = fmaf(a0.x, w[0], acc);
      acc = fmaf(a0.y, w[1], acc);
      acc = fmaf(a0.z, w[2], acc);
      acc = fmaf(a0.w, w[3], acc);
      acc = fmaf(a1.x, w[4], acc);
      acc = fmaf(a1.y, w[5], acc);
      acc = fmaf(a1.z, w[6], acc);
      acc = fmaf(a1.w, w[7], acc);
    }
    float* O = (kz == 0) ? y2a : y2b;
    O[(size_t)(tok0 + wv) * HH + c] = acc;
  }
}

// ---------------------------------------------------------------------------
// Score kernel (R12 shape): bf16 P gather + precomputed bf16 gmat.
// grid 2048 = (b,i) x j-half; 256 threads.  Wave w handles tiles {w, 7-w}.
// ---------------------------------------------------------------------------
#define RSTR 164
#define SCP  132   // sc_s row stride

__global__ __launch_bounds__(256, 4) void k_score(
    const float* __restrict__ qb, const float* __restrict__ kb,
    const __hip_bfloat16* __restrict__ gmat_bf,
    const __hip_bfloat16* __restrict__ Pbf,
    const int* __restrict__ pos_s, const int* __restrict__ pos_e,
    const int* __restrict__ seq_len, const int* __restrict__ lex_num,
    const float* __restrict__ utab, float* __restrict__ scores) {
  int bid = blockIdx.x;
  int blk = bid >> 1;          // b*S + i
  int half = bid & 1;
  int b = blk >> 8;
  int i = blk & 255;
  int t = threadIdx.x;
  int limit = seq_len[b] + lex_num[0];
  if (half * 128 >= limit) return;   // whole half masked (uniform)

  __shared__ __align__(16) float qu[HH];
  __shared__ __align__(16) float g_s[NH_][RSTR];
  __shared__ __align__(16) float sc_s[NH_][SCP];
  __shared__ int ps_s[SS], pe_s[SS];

  if (t < HH) qu[t] = qb[(size_t)blk * HH + t] + utab[t];
  ps_s[t] = pos_s[b * SS + t];
  pe_s[t] = pos_e[b * SS + t];
  // g load: 160 uint4 = 1280 bf16, coalesced; unpack to f32 LDS
  if (t < 160) {
    const uint4* gsrc = (const uint4*)(gmat_bf + (size_t)blk * (NH_ * HH));
    uint4 u = gsrc[t];
    int h = t / 20, c8 = (t - h * 20) * 8;
    g_s[h][c8 + 0] = blo(u.x); g_s[h][c8 + 1] = bhi(u.x);
    g_s[h][c8 + 2] = blo(u.y); g_s[h][c8 + 3] = bhi(u.y);
    g_s[h][c8 + 4] = blo(u.z); g_s[h][c8 + 5] = bhi(u.z);
    g_s[h][c8 + 6] = blo(u.w); g_s[h][c8 + 7] = bhi(u.w);
  }
  __syncthreads();

  int w = t >> 6, lane = t & 63;
  int jj = lane >> 2, cg = lane & 3;
  int psi = ps_s[i], pei = pe_s[i];
  const float scale = 0.22360679774997896f;  // 1/sqrt(20)

  // bf16 planes: row stride = 160*2B = 20 uint4; plane = 512 rows.
  const uint4* Pb0 = (const uint4*)Pbf;
  const uint4* Pb1 = Pb0 + (size_t)PROWS * 20;
  const uint4* Pb2 = Pb1 + (size_t)PROWS * 20;
  const uint4* Pb3 = Pb2 + (size_t)PROWS * 20;
  const float4* kb4 = (const float4*)(kb + (size_t)b * SS * HH);

  #pragma unroll
  for (int pass = 0; pass < 2; ++pass) {
    int tau = (pass == 0) ? w : 7 - w;
    int jl = tau * 16 + jj;          // 0..127
    int j = half * 128 + jl;
    if (half * 128 + tau * 16 >= limit) continue;   // tile fully masked
    int psj = ps_s[j], pej = pe_s[j];
    int r0b = (psi - psj + 256) * 20;
    int r1b = (psi - pej + 256) * 20;
    int r2b = (pei - psj + 256) * 20;
    int r3b = (pei - pej + 256) * 20;
    float bd[NH_];
    #pragma unroll
    for (int h = 0; h < NH_; ++h) bd[h] = 0.0f;
    // gather: 4 uint4 (32 bf16) -> unpack -> relu -> 64 FMAs, per q5
    #pragma unroll 2
    for (int q5 = 0; q5 < 5; ++q5) {
      int off = q5 * 4 + cg;
      uint4 u0 = Pb0[r0b + off];
      uint4 u1 = Pb1[r1b + off];
      uint4 u2 = Pb2[r2b + off];
      uint4 u3 = Pb3[r3b + off];
      float rl[8];
      rl[0] = fmaxf(blo(u0.x) + blo(u1.x) + blo(u2.x) + blo(u3.x), 0.0f);
      rl[1] = fmaxf(bhi(u0.x) + bhi(u1.x) + bhi(u2.x) + bhi(u3.x), 0.0f);
      rl[2] = fmaxf(blo(u0.y) + blo(u1.y) + blo(u2.y) + blo(u3.y), 0.0f);
      rl[3] = fmaxf(bhi(u0.y) + bhi(u1.y) + bhi(u2.y) + bhi(u3.y), 0.0f);
      rl[4] = fmaxf(blo(u0.z) + blo(u1.z) + blo(u2.z) + blo(u3.z), 0.0f);
      rl[5] = fmaxf(bhi(u0.z) + bhi(u1.z) + bhi(u2.z) + bhi(u3.z), 0.0f);
      rl[6] = fmaxf(blo(u0.w) + blo(u1.w) + blo(u2.w) + blo(u3.w), 0.0f);
      rl[7] = fmaxf(bhi(u0.w) + bhi(u1.w) + bhi(u2.w) + bhi(u3.w), 0.0f);
      int cb = off * 8;
      #pragma unroll
      for (int h = 0; h < NH_; ++h) {
        float4 ga = *(const float4*)&g_s[h][cb];
        float4 gb = *(const float4*)&g_s[h][cb + 4];
        bd[h] = fmaf(rl[0], ga.x, bd[h]);
        bd[h] = fmaf(rl[1], ga.y, bd[h]);
        bd[h] = fmaf(rl[2], ga.z, bd[h]);
        bd[h] = fmaf(rl[3], ga.w, bd[h]);
        bd[h] = fmaf(rl[4], gb.x, bd[h]);
        bd[h] = fmaf(rl[5], gb.y, bd[h]);
        bd[h] = fmaf(rl[6], gb.z, bd[h]);
        bd[h] = fmaf(rl[7], gb.w, bd[h]);
      }
    }
    // A_C for heads 2cg, 2cg+1 : c in [40cg, 40cg+40)
    float ac0 = 0.0f, ac1 = 0.0f;
    {
      int kbase = j * 40 + 10 * cg;
      #pragma unroll
      for (int m = 0; m < 10; ++m) {
        float4 kv = kb4[kbase + m];
        float4 q4 = *(const float4*)&qu[(10 * cg + m) * 4];
        if (m < 5) {
          ac0 = fmaf(q4.x, kv.x, ac0); ac0 = fmaf(q4.y, kv.y, ac0);
          ac0 = fmaf(q4.z, kv.z, ac0); ac0 = fmaf(q4.w, kv.w, ac0);
        } else {
          ac1 = fmaf(q4.x, kv.x, ac1); ac1 = fmaf(q4.y, kv.y, ac1);
          ac1 = fmaf(q4.z, kv.z, ac1); ac1 = fmaf(q4.w, kv.w, ac1);
        }
      }
    }
    // reduce bd over the 4 cg lanes
    #pragma unroll
    for (int h = 0; h < NH_; ++h) {
      bd[h] += __shfl_xor(bd[h], 1);
      bd[h] += __shfl_xor(bd[h], 2);
    }
    float s0, s1;
    if      (cg == 0) { s0 = bd[0]; s1 = bd[1]; }
    else if (cg == 1) { s0 = bd[2]; s1 = bd[3]; }
    else if (cg == 2) { s0 = bd[4]; s1 = bd[5]; }
    else              { s0 = bd[6]; s1 = bd[7]; }
    sc_s[2 * cg][jl]     = (s0 + ac0) * scale;
    sc_s[2 * cg + 1][jl] = (s1 + ac1) * scale;
  }
  __syncthreads();

  // coalesced writeout: 8 rows x 32 float4
  {
    int row = t >> 5, c4 = t & 31;
    float4 v = *(const float4*)&sc_s[row][c4 * 4];
    *(float4*)&scores[((size_t)blk * NH_ + row) * SS + half * 128 + c4 * 4] = v;
  }
}

// ---------------------------------------------------------------------------
// Softmax + PV + W_fin fused: grid 1024, 256 threads.
// ---------------------------------------------------------------------------
#define SCS 260

__global__ __launch_bounds__(256, 4) void k_smpv(
    const float* __restrict__ scores, const float* __restrict__ vb,
    const int* __restrict__ seq_len, const int* __restrict__ lex_num,
    const float* __restrict__ W_fin, const float* __restrict__ b_fin,
    float* __restrict__ ybuf) {
  int blk = blockIdx.x;
  int b = blk >> 8;
  int t = threadIdx.x;
  __shared__ __align__(16) float sc[NH_][SCS];
  __shared__ __align__(16) float outs[HH];
  int limit = seq_len[b] + lex_num[0];

  const float4* src = (const float4*)(scores + (size_t)blk * NH_ * SS);
  #pragma unroll
  for (int r = 0; r < 2; ++r) {
    int idx = r * 256 + t;
    int row = idx >> 6, c4 = idx & 63;
    float4 v = src[idx];
    int j0 = c4 * 4;
    v.x = (j0 + 0 < limit) ? v.x : -1.0e15f;
    v.y = (j0 + 1 < limit) ? v.y : -1.0e15f;
    v.z = (j0 + 2 < limit) ? v.z : -1.0e15f;
    v.w = (j0 + 3 < limit) ? v.w : -1.0e15f;
    *(float4*)&sc[row][j0] = v;
  }
  __syncthreads();

  {
    int h = t >> 5, l = t & 31;
    float m = -3.0e38f;
    float e[8];
    #pragma unroll
    for (int ii = 0; ii < 8; ++ii) m = fmaxf(m, sc[h][l + ii * 32]);
    #pragma unroll
    for (int msk = 16; msk; msk >>= 1) m = fmaxf(m, __shfl_xor(m, msk));
    float s = 0.0f;
    #pragma unroll
    for (int ii = 0; ii < 8; ++ii) { e[ii] = __expf(sc[h][l + ii * 32] - m); s += e[ii]; }
    #pragma unroll
    for (int msk = 16; msk; msk >>= 1) s += __shfl_xor(s, msk);
    float inv = 1.0f / s;
    #pragma unroll
    for (int ii = 0; ii < 8; ++ii) sc[h][l + ii * 32] = e[ii] * inv;
  }
  __syncthreads();

  if (t < HH) {
    int h = t / HD_;
    int lim4 = (limit + 3) & ~3;
    float acc0 = 0.f, acc1 = 0.f, acc2 = 0.f, acc3 = 0.f;
    const float* vcol = vb + (size_t)b * SS * HH + t;
    for (int j2 = 0; j2 < lim4; j2 += 4) {
      float4 p4 = *(const float4*)&sc[h][j2];
      acc0 = fmaf(p4.x, vcol[(size_t)(j2 + 0) * HH], acc0);
      acc1 = fmaf(p4.y, vcol[(size_t)(j2 + 1) * HH], acc1);
      acc2 = fmaf(p4.z, vcol[(size_t)(j2 + 2) * HH], acc2);
      acc3 = fmaf(p4.w, vcol[(size_t)(j2 + 3) * HH], acc3);
    }
    outs[t] = (acc0 + acc1) + (acc2 + acc3);
  }
  __syncthreads();

  // W_fin: y[t] = b_fin[t] + sum_c outs[c] * W_fin[c*160 + t]
  if (t < HH) {
    float acc = b_fin[t];
    const float* wp = W_fin + t;
    #pragma unroll 8
    for (int c = 0; c < HH; ++c)
      acc = fmaf(outs[c], wp[(size_t)c * HH], acc);
    ybuf[(size_t)blk * HH + t] = acc;
  }
}

// ---------------------------------------------------------------------------
// Final LayerNorm over sum of split-K partials.
// ---------------------------------------------------------------------------
__global__ __launch_bounds__(256) void k_ln2(
    const float* __restrict__ Ya, const float* __restrict__ Yb,
    const float* __restrict__ g, const float* __restrict__ bln,
    float* __restrict__ O) {
  int tok = blockIdx.x * 4 + (threadIdx.x >> 6);
  int l = threadIdx.x & 63;
  const float* ya = Ya + (size_t)tok * HH;
  const float* yb = Yb + (size_t)tok * HH;
  float a = ya[l] + yb[l];
  float bv = ya[l + 64] + yb[l + 64];
  bool has3 = l < (HH - 128);
  float cv = has3 ? (ya[l + 128] + yb[l + 128]) : 0.0f;
  float s = a + bv + cv;
  #pragma unroll
  for (int m = 32; m; m >>= 1) s += __shfl_xor(s, m);
  float mu = s * (1.0f / HH);
  float da = a - mu, db = bv - mu, dc = has3 ? (cv - mu) : 0.0f;
  float s2 = da * da + db * db + dc * dc;
  #pragma unroll
  for (int m = 32; m; m >>= 1) s2 += __shfl_xor(s2, m);
  float rstd = rsqrtf(s2 * (1.0f / HH) + 2.5e-6f);  // eps 1e-5 / 4
  float* o = O + (size_t)tok * HH;
  o[l]      = da * rstd * g[l] + bln[l];
  o[l + 64] = db * rstd * g[l + 64] + bln[l + 64];
  if (has3) o[l + 128] = dc * rstd * g[l + 128] + bln[l + 128];
}

// ---------------------------------------------------------------------------
extern "C" void kernel_launch(void* const* d_in, const int* in_sizes, int n_in,
                              void* d_out, int out_size, void* d_ws, size_t ws_size,
                              hipStream_t stream) {
  const float* inp    = (const float*)d_in[0];
  const int*   pos_s  = (const int*)d_in[1];
  const int*   pos_e  = (const int*)d_in[2];
  const int*   seq_ln = (const int*)d_in[3];
  const int*   lex_nm = (const int*)d_in[4];
  const float* pe_ss  = (const float*)d_in[5];
  const float* pe_se  = (const float*)d_in[6];
  const float* pe_es  = (const float*)d_in[7];
  const float* pe_ee  = (const float*)d_in[8];
  const float* W_fus  = (const float*)d_in[9];
  const float* b_fus  = (const float*)d_in[10];
  const float* Wq     = (const float*)d_in[11];
  const float* bq     = (const float*)d_in[12];
  const float* Wk     = (const float*)d_in[13];
  const float* bk     = (const float*)d_in[14];
  const float* Wv     = (const float*)d_in[15];
  const float* bv     = (const float*)d_in[16];
  const float* Wr     = (const float*)d_in[17];
  // d_in[18] = br : constant-over-j term, cancels in softmax
  const float* utab   = (const float*)d_in[19];
  const float* vtab   = (const float*)d_in[20];
  const float* W_fin  = (const float*)d_in[21];
  const float* b_fin  = (const float*)d_in[22];
  const float* ln1_g  = (const float*)d_in[23];
  const float* ln1_b  = (const float*)d_in[24];
  const float* W1     = (const float*)d_in[25];
  const float* b1     = (const float*)d_in[26];
  const float* W2     = (const float*)d_in[27];
  const float* b2     = (const float*)d_in[28];
  const float* ln2_g  = (const float*)d_in[29];
  const float* ln2_b  = (const float*)d_in[30];

  float* ws = (float*)d_ws;
  __hip_bfloat16* Pbf = (__hip_bfloat16*)ws;          // 4*512*160 bf16 = 655360 B
  float* qb       = ws + 163840;
  float* kb       = qb + BB * SS * HH;
  float* vb       = kb + BB * SS * HH;
  float* WrT      = vb + BB * SS * HH;                // 25600
  float* gregion  = WrT + HH * HH;                    // 655360 float-slots
  __hip_bfloat16* gmat_bf = (__hip_bfloat16*)gregion; //   1024*1280 bf16
  float* ybuf     = gregion;                          //   aliases gmat (dead after k_score)
  float* scores   = gregion + 655360;                 // 2097152 (1024*8*256)
  // scores dead after k_smpv; alias FFN buffers over it:
  float* hbuf     = scores;                           // 655360
  float* y2a      = scores + 655360;                  // 163840
  float* y2b      = scores + 819200;                  // 163840

  (void)in_sizes; (void)n_in; (void)out_size; (void)ws_size;

  const int M = BB * SS;  // 1024

  k_setup<<<WRT_END, 256, 0, stream>>>(pe_ss, pe_se, pe_es, pe_ee, W_fus, b_fus,
                                       inp, Wq, bq, Wk, bk, Wv, bv, Wr,
                                       Pbf, qb, kb, vb, WrT);
  k_gmat<<<M / 4, 256, 0, stream>>>(qb, vtab, WrT, gmat_bf);
  k_score<<<2 * M, 256, 0, stream>>>(qb, kb, gmat_bf, Pbf, pos_s, pos_e,
                                     seq_ln, lex_nm, utab, scores);
  k_smpv<<<M, 256, 0, stream>>>(scores, vb, seq_ln, lex_nm, W_fin, b_fin, ybuf);
  k_ffn1<<<dim3(M / 8, 10), 256, 0, stream>>>(ybuf, ln1_g, ln1_b, W1, b1, hbuf);
  k_w2<<<dim3(M / 4, 3, 2), 256, 0, stream>>>(hbuf, W2, b2, y2a, y2b);
  k_ln2<<<M / 4, 256, 0, stream>>>(y2a, y2b, ln2_g, ln2_b, (float*)d_out);
}